// Round 22
// baseline (582.893 us; speedup 1.0000x reference)
//
#include <hip/hip_runtime.h>
#include <hip/hip_bf16.h>
#include <math.h>
#include <stdint.h>

#define N_BATCH 2048
#define T_STEPS 50
#define NCODES  40
#define MH      526
#define AUXD    10
#define WLROWS  536    // MH + AUXD
#define E_DIM   256
#define G_DIM   1024   // 4*E
#define TCHUNK  10     // time steps per fused chunk (5 chunks)
#define MBLK    64     // (n,t) rows per fused block
#define NFUSED  (TCHUNK * 32)   // 320 fused blocks per chunk

typedef __attribute__((ext_vector_type(8))) short short8;   // 8 bf16 = 4 VGPR
typedef __attribute__((ext_vector_type(4))) short short4v;  // 4 bf16 = 2 VGPR
typedef __attribute__((ext_vector_type(4))) float f32x4;
typedef __attribute__((ext_vector_type(4))) int   i32x4;    // asm-safe 16B

__device__ __forceinline__ short f2bf(float f) {
    __hip_bfloat16 h = __float2bfloat16(f);
    return *reinterpret_cast<short*>(&h);
}
__device__ __forceinline__ float bf2f(unsigned short u) {
    return __uint_as_float(((unsigned int)u) << 16);
}
__device__ __forceinline__ float sigf(float x) {
    return 1.f / (1.f + __expf(-x));
}
__device__ __forceinline__ float tanhfast(float x) {
    return 2.f / (1.f + __expf(-2.f * x)) - 1.f;
}

// ---------------------------------------------------------------------------
// Zero peer-barrier slots: 3 regions x 32 rgps x 32-int stride (128B lines).
// ---------------------------------------------------------------------------
__global__ __launch_bounds__(256) void k_zero(int* __restrict__ cnt)
{
    const int i = blockIdx.x * 256 + threadIdx.x;
    if (i < 3 * 32 * 32) cnt[i] = 0;
}

// ---------------------------------------------------------------------------
// Wcoop: R pre-permuted for rcoop register residency.
// fg = ((cs*4 + w)*4 + g)*8 + kk ; Wcoop[fg*512 + lane*8 + j]
//   = R[kk*32 + p*8 + j][g*256 + cs*64 + w*16 + lr]
// ---------------------------------------------------------------------------
__global__ __launch_bounds__(256) void k_prep_wcoop(
    const float* __restrict__ R, short* __restrict__ Wcoop)
{
    const int gid  = blockIdx.x * 256 + threadIdx.x;   // 32768
    const int fg   = gid >> 6, lane = gid & 63;
    const int p    = lane >> 4, lr = lane & 15;
    const int kk   = fg & 7;
    const int g    = (fg >> 3) & 3;
    const int w    = (fg >> 5) & 3;
    const int cs   = fg >> 7;
    const int n    = g * 256 + cs * 64 + w * 16 + lr;
    short* dst = Wcoop + (size_t)fg * 512 + lane * 8;
    #pragma unroll
    for (int j = 0; j < 8; ++j)
        dst[j] = f2bf(R[(size_t)(kk * 32 + p * 8 + j) * G_DIM + n]);
}

// WfK (K for fused phase 3): fg = (kb*8 + cb)*8 + w
__global__ __launch_bounds__(256) void k_prep_wfk(
    const float* __restrict__ K, short* __restrict__ WfK)
{
    const int gid  = blockIdx.x * 256 + threadIdx.x;   // 32768
    const int fg   = gid >> 6, lane = gid & 63;
    const int p    = lane >> 4, lr = lane & 15;
    const int kb   = fg >> 6;
    const int cb   = (fg >> 3) & 7;
    const int w    = fg & 7;
    const int n    = w * 128 + cb * 16 + lr;
    short* dst = WfK + (size_t)fg * 512 + lane * 8;
    #pragma unroll
    for (int j = 0; j < 8; ++j)
        dst[j] = f2bf(K[(size_t)(kb * 32 + p * 8 + j) * G_DIM + n]);
}

// WfL (W_lin for fused phase 2): fg = (kk*2 + cb)*8 + w, kk 0..16
__global__ __launch_bounds__(256) void k_prep_wfl(
    const float* __restrict__ W_lin, short* __restrict__ WfL)
{
    const int gid  = blockIdx.x * 256 + threadIdx.x;   // 17408
    const int fg   = gid >> 6, lane = gid & 63;
    const int p    = lane >> 4, lr = lane & 15;
    const int kk   = fg >> 4;
    const int cb   = (fg >> 3) & 1;
    const int w    = fg & 7;
    const int n    = w * 32 + cb * 16 + lr;
    short* dst = WfL + (size_t)fg * 512 + lane * 8;
    #pragma unroll
    for (int j = 0; j < 8; ++j) {
        const int k = kk * 32 + p * 8 + j;
        dst[j] = (k < WLROWS) ? f2bf(W_lin[(size_t)k * E_DIM + n]) : (short)0;
    }
}

// ---------------------------------------------------------------------------
// Fused embed + xz GEMM (R16-validated body, unchanged).
// ---------------------------------------------------------------------------
__global__ __launch_bounds__(512, 1) void k_fused(
    const int* __restrict__ code, const float* __restrict__ aux,
    const short* __restrict__ WfL, const float* __restrict__ b_lin,
    const short* __restrict__ WfK, short* __restrict__ xzp, int t0f)
{
    const int tid  = threadIdx.x;
    const int w    = tid >> 6;
    const int lane = tid & 63;
    const int lr   = lane & 15;
    const int p    = lane >> 4;
    const int fid  = blockIdx.x;
    const int tl   = fid >> 5;                 // 0..TCHUNK-1
    const int ngg  = fid & 31;
    const int n0   = ngg * MBLK;               // 64 consecutive batch rows
    const int t    = t0f + tl;
    const int ph8  = (fid >> 3) & 7;
    const int ph17 = (fid >> 3) % 17;

    __shared__ __align__(16) short oh[MBLK][552];   // 70656 B
    __shared__ __align__(16) short xs[MBLK][264];   // 33792 B

    for (int i = tid; i < (MBLK * 552) / 8; i += 512)
        ((int4*)&oh[0][0])[i] = (int4){0, 0, 0, 0};
    __syncthreads();

    for (int i = tid; i < MBLK * NCODES; i += 512) {
        const int r = i / NCODES;
        const int j = i - r * NCODES;
        const int c = code[((size_t)(n0 + r) * T_STEPS + t) * NCODES + j];
        if (c > 0) ((unsigned short*)&oh[0][0])[r * 552 + (c - 1)] = 0x3F80;
    }
    for (int i = tid; i < MBLK * AUXD; i += 512) {
        const int r = i / AUXD;
        const int a = i - r * AUXD;
        oh[r][MH + a] = f2bf(aux[((size_t)(n0 + r) * T_STEPS + t) * AUXD + a]);
    }
    __syncthreads();

    const short* wfl_thr = WfL + (size_t)w * 512 + lane * 8;
    const short* wfk_thr = WfK + (size_t)w * 512 + lane * 8;

    // ---- Phase 2: xs = relu(oh @ WfL^T + b_lin) ----
    {
        f32x4 acc[4][2];
        #pragma unroll
        for (int rb = 0; rb < 4; ++rb)
            #pragma unroll
            for (int cb = 0; cb < 2; ++cb)
                acc[rb][cb] = (f32x4){0.f, 0.f, 0.f, 0.f};

        for (int kk = 0; kk < 17; ++kk) {
            int kx = kk + ph17; if (kx >= 17) kx -= 17;
            short8 a[4];
            #pragma unroll
            for (int rb = 0; rb < 4; ++rb)
                a[rb] = *(const short8*)&oh[rb * 16 + lr][kx * 32 + p * 8];
            #pragma unroll
            for (int cb = 0; cb < 2; ++cb) {
                short8 bf = *(const short8*)(wfl_thr + (size_t)(kx * 2 + cb) * 4096);
                #pragma unroll
                for (int rb = 0; rb < 4; ++rb)
                    acc[rb][cb] = __builtin_amdgcn_mfma_f32_16x16x32_bf16(
                        a[rb], bf, acc[rb][cb], 0, 0, 0);
            }
        }
        float bias[2];
        #pragma unroll
        for (int cb = 0; cb < 2; ++cb) bias[cb] = b_lin[w * 32 + cb * 16 + lr];
        #pragma unroll
        for (int rb = 0; rb < 4; ++rb)
            #pragma unroll
            for (int cb = 0; cb < 2; ++cb)
                #pragma unroll
                for (int rr = 0; rr < 4; ++rr)
                    xs[rb * 16 + p * 4 + rr][w * 32 + cb * 16 + lr] =
                        f2bf(fmaxf(acc[rb][cb][rr] + bias[cb], 0.f));
        __syncthreads();
    }

    // ---- Phase 3: xz = xs @ WfK^T, frag-order output ----
    #pragma unroll
    for (int half = 0; half < 2; ++half) {
        f32x4 acc[4][4];
        #pragma unroll
        for (int rb = 0; rb < 4; ++rb)
            #pragma unroll
            for (int c4 = 0; c4 < 4; ++c4)
                acc[rb][c4] = (f32x4){0.f, 0.f, 0.f, 0.f};

        for (int kb = 0; kb < 8; ++kb) {
            const int kx = (kb + ph8) & 7;
            short8 a[4];
            #pragma unroll
            for (int rb = 0; rb < 4; ++rb)
                a[rb] = *(const short8*)&xs[rb * 16 + lr][kx * 32 + p * 8];
            #pragma unroll
            for (int c4 = 0; c4 < 4; ++c4) {
                const int cb = half * 4 + c4;
                short8 bf = *(const short8*)(wfk_thr + (size_t)(kx * 8 + cb) * 4096);
                #pragma unroll
                for (int rb = 0; rb < 4; ++rb)
                    acc[rb][c4] = __builtin_amdgcn_mfma_f32_16x16x32_bf16(
                        a[rb], bf, acc[rb][c4], 0, 0, 0);
            }
        }
        #pragma unroll
        for (int rb = 0; rb < 4; ++rb) {
            const int rgg = ngg * 4 + rb;   // global 16-row group
            #pragma unroll
            for (int c4 = 0; c4 < 4; ++c4) {
                const int cb = half * 4 + c4;
                const int c0 = w * 128 + cb * 16;
                const int g  = c0 >> 8;
                const int wp = (c0 >> 5) & 7;
                const int eb = (c0 >> 4) & 1;
                const int j8 = eb * 4 + g;
                short4v v;
                #pragma unroll
                for (int rr = 0; rr < 4; ++rr) v[rr] = f2bf(acc[rb][c4][rr]);
                *(short4v*)(xzp +
                    (((size_t)rgg * TCHUNK + tl) * 64 + wp * 8 + j8) * 256 +
                    lane * 4) = v;
            }
        }
    }
}

// ---------------------------------------------------------------------------
// Recurrence v15 = R21 staging (coalesced sc load + ^kk-swizzled LDS) +
// R20 rg-pairing: 128 blocks = cs(4) x rgp(32), block owns 64 rows
// (2 independent 32-row groups). One stage + ONE barrier per superstep
// serves both rgs -> fixed serial chain amortized 2x. Weights register-
// resident (shared by both rgs); slot barrier; parity h_buf.
// ---------------------------------------------------------------------------
__global__ __launch_bounds__(256, 1) void k_rcoop(
    const short* __restrict__ xz0, const short* __restrict__ xz1,
    const int* __restrict__ length,
    const short* __restrict__ Wcoop, const float* __restrict__ b,
    short* __restrict__ h_buf, float* __restrict__ c_state,
    float* __restrict__ xlast, int* __restrict__ flags,
    int t0, int nsteps)
{
    const int tid  = threadIdx.x;
    const int w    = tid >> 6;          // 0..3
    const int lane = tid & 63;
    const int lr   = lane & 15;
    const int p    = lane >> 4;
    const int cs   = blockIdx.x >> 5;   // 0..3
    const int rgp  = blockIdx.x & 31;   // 0..31 (64-row pair group)
    const int r0   = rgp * 64;
    const int e    = cs * 64 + w * 16 + lr;

    __shared__ __align__(16) short h_f[2][2][8][512];  // swizzled, 32 KB
    __shared__ __align__(16) short h_o[2][32][64];     // own-slice, 8 KB
    __shared__ int s_len[64];
    if (tid < 64) s_len[tid] = length[r0 + tid];

    // ---- R slice -> registers (resident, shared by both rgs) ----
    short8 bw[4][8];
    {
        const short* wb = Wcoop + ((size_t)((cs * 4 + w) * 4)) * 8 * 512 + lane * 8;
        #pragma unroll
        for (int g = 0; g < 4; ++g)
            #pragma unroll
            for (int kk = 0; kk < 8; ++kk)
                bw[g][kk] = *(const short8*)(wb + (size_t)(g * 8 + kk) * 512);
    }

    float bias[4];
    #pragma unroll
    for (int g = 0; g < 4; ++g) bias[g] = b[g * 256 + e];

    float creg[2][2][4];
    if (t0 == 0) {
        #pragma unroll
        for (int rg = 0; rg < 2; ++rg)
            #pragma unroll
            for (int rf = 0; rf < 2; ++rf)
                #pragma unroll
                for (int rr = 0; rr < 4; ++rr) creg[rg][rf][rr] = 0.f;
    } else {
        #pragma unroll
        for (int rg = 0; rg < 2; ++rg)
            #pragma unroll
            for (int rf = 0; rf < 2; ++rf)
                #pragma unroll
                for (int rr = 0; rr < 4; ++rr)
                    creg[rg][rf][rr] = c_state[
                        (size_t)(r0 + rg * 32 + rf * 16 + p * 4 + rr) * E_DIM + e];
    }
    __syncthreads();

    int len_r[2][2][4];
    #pragma unroll
    for (int rg = 0; rg < 2; ++rg)
        #pragma unroll
        for (int rf = 0; rf < 2; ++rf)
            #pragma unroll
            for (int rr = 0; rr < 4; ++rr)
                len_r[rg][rf][rr] = s_len[rg * 32 + rf * 16 + p * 4 + rr];

    const uint64_t slot_addr = (uint64_t)(uintptr_t)(flags + rgp * 32 + cs);
    const uint64_t line_addr = (uint64_t)(uintptr_t)(flags + rgp * 32);
    int bcnt = 0;

#define PEERS_BARRIER()                                                        \
    do {                                                                       \
        ++bcnt;                                                                \
        __syncthreads(); /* drains vmcnt: sc h-stores complete */              \
        if (tid == 0) {                                                        \
            asm volatile("global_store_dword %0, %1, off sc0 sc1"              \
                         :: "v"(slot_addr), "v"(bcnt) : "memory");             \
            i32x4 fv;                                                          \
            do {                                                               \
                asm volatile("global_load_dwordx4 %0, %1, off sc0 sc1\n\t"     \
                             "s_waitcnt vmcnt(0)"                              \
                             : "=v"(fv) : "v"(line_addr) : "memory");          \
            } while (fv[0] < bcnt || fv[1] < bcnt ||                           \
                     fv[2] < bcnt || fv[3] < bcnt);                            \
        }                                                                      \
        __syncthreads();                                                       \
    } while (0)

    // ---- chunk-0 init: zero own slices of h_buf parity 0 (64 rows) ----
    if (t0 == 0) {
        const i32x4 z4 = {0, 0, 0, 0};
        #pragma unroll
        for (int rep = 0; rep < 2; ++rep) {
            const int idx = tid + rep * 256;
            const int row = idx >> 3, seg = idx & 7;   // 64 rows x 8 segs
            const uint64_t dst = (uint64_t)(uintptr_t)(h_buf +
                (size_t)(r0 + row) * E_DIM + cs * 64 + seg * 8);
            asm volatile("global_store_dwordx4 %0, %1, off sc0 sc1"
                         :: "v"(dst), "v"(z4) : "memory");
        }
        PEERS_BARRIER();
    }

    // hoisted invariants
    const short* hb0 = h_buf;
    const short* hb1 = h_buf + (size_t)N_BATCH * E_DIM;
    const size_t coloff = (size_t)((cs * 2 + (w >> 1)) * 8 + (w & 1) * 4) * 256 +
                          lane * 4;   // + g*256 per gate
    size_t rowoff[2][2];
    #pragma unroll
    for (int rg = 0; rg < 2; ++rg)
        #pragma unroll
        for (int rf = 0; rf < 2; ++rf)
            rowoff[rg][rf] = (size_t)(rgp * 4 + rg * 2 + rf) * TCHUNK * 16384;

#define XZ_BASE(T, RFOFF)                                                      \
    ((((((T) / TCHUNK) & 1) ? xz1 : xz0)) + (RFOFF) +                          \
     (size_t)((T) % TCHUNK) * 16384 + coloff)

    // ---- prefetch xz for first step ----
    short4v xv[2][2][4];
    #pragma unroll
    for (int rg = 0; rg < 2; ++rg)
        #pragma unroll
        for (int rf = 0; rf < 2; ++rf) {
            const short* bp = XZ_BASE(t0, rowoff[rg][rf]);
            #pragma unroll
            for (int g = 0; g < 4; ++g)
                xv[rg][rf][g] = *(const short4v*)(bp + g * 256);
        }

    // coop-load geometry: 8 chunks/thread over 2rg x 32row x 32ch
    const int ld_ch = tid & 31;
    const int ld_kk = ld_ch >> 2;

    for (int s = 0; s < nsteps; ++s) {
        const int t = t0 + s;
        const short* hb_r = (t & 1) ? hb1 : hb0;

        // ---- stage h(t) for BOTH rgs: coalesced sc0sc1 -> swizzled LDS ----
        {
            short8 ld[8];
            #pragma unroll
            for (int it = 0; it < 8; ++it) {
                const int idx = tid + it * 256;      // rg = idx>>10
                const int rg  = idx >> 10;
                const int row = (idx & 1023) >> 5;   // 0..31
                const uint64_t src = (uint64_t)(uintptr_t)(hb_r +
                    (size_t)(r0 + rg * 32 + row) * E_DIM + ld_ch * 8);
                asm volatile("global_load_dwordx4 %0, %1, off sc0 sc1"
                             : "=&v"(ld[it]) : "v"(src) : "memory");
            }
            asm volatile("s_waitcnt vmcnt(0)" ::: "memory");
            #pragma unroll
            for (int it = 0; it < 8; ++it) {
                const int idx = tid + it * 256;
                const int rg  = idx >> 10;
                const int row = (idx & 1023) >> 5;
                const int slot = (((ld_ch & 3) * 16) + (row & 15)) ^ ld_kk;
                *(short8*)&h_f[rg][row >> 4][ld_kk][slot * 8] = ld[it];
            }
        }
        __syncthreads();

        // ---- compute both row-groups (shared register weights) ----
        #pragma unroll
        for (int rg = 0; rg < 2; ++rg) {
            f32x4 acc[2][4];
            #pragma unroll
            for (int rf = 0; rf < 2; ++rf)
                #pragma unroll
                for (int g = 0; g < 4; ++g)
                    #pragma unroll
                    for (int rr = 0; rr < 4; ++rr)
                        acc[rf][g][rr] = bf2f((unsigned short)xv[rg][rf][g][rr]);

            #pragma unroll
            for (int kk = 0; kk < 8; ++kk) {
                const int sl = (lane ^ kk) * 8;
                short8 a0 = *(const short8*)&h_f[rg][0][kk][sl];
                short8 a1 = *(const short8*)&h_f[rg][1][kk][sl];
                #pragma unroll
                for (int g = 0; g < 4; ++g) {
                    acc[0][g] = __builtin_amdgcn_mfma_f32_16x16x32_bf16(
                        a0, bw[g][kk], acc[0][g], 0, 0, 0);
                    acc[1][g] = __builtin_amdgcn_mfma_f32_16x16x32_bf16(
                        a1, bw[g][kk], acc[1][g], 0, 0, 0);
                }
            }

            #pragma unroll
            for (int rf = 0; rf < 2; ++rf) {
                #pragma unroll
                for (int rr = 0; rr < 4; ++rr) {
                    float zi = acc[rf][0][rr] + bias[0];
                    float zf = acc[rf][1][rr] + bias[1];
                    float zg = acc[rf][2][rr] + bias[2];
                    float zo = acc[rf][3][rr] + bias[3];
                    float ig = sigf(zi), fg = sigf(zf);
                    float gg = tanhfast(zg), og = sigf(zo);
                    float cc = fg * creg[rg][rf][rr] + ig * gg;
                    float hh = og * tanhfast(cc);
                    creg[rg][rf][rr] = cc;
                    h_o[rg][rf * 16 + p * 4 + rr][w * 16 + lr] = f2bf(hh);
                    const int row = r0 + rg * 32 + rf * 16 + p * 4 + rr;
                    if (t == len_r[rg][rf][rr] - 1)
                        xlast[(size_t)row * E_DIM + e] = hh;
                }
            }
        }

        // next-step xz prefetch (may cross chunk parity)
        if (s + 1 < nsteps) {
            #pragma unroll
            for (int rg = 0; rg < 2; ++rg)
                #pragma unroll
                for (int rf = 0; rf < 2; ++rf) {
                    const short* bp = XZ_BASE(t + 1, rowoff[rg][rf]);
                    #pragma unroll
                    for (int g = 0; g < 4; ++g)
                        xv[rg][rf][g] = *(const short4v*)(bp + g * 256);
                }
        }

        __syncthreads();   // h_o complete (also guards h_f reuse next step)

        // ---- coalesced sc0sc1 store of both own h(t+1) slices ----
        {
            short* hb_w = (short*)(((t + 1) & 1) ? hb1 : hb0);
            #pragma unroll
            for (int rep = 0; rep < 2; ++rep) {
                const int idx = tid + rep * 256;     // rg = idx>>8
                const int rg  = idx >> 8;
                const int row = (idx & 255) >> 3, seg = idx & 7;
                i32x4 v = *(const i32x4*)&h_o[rg][row][seg * 8];
                const uint64_t dst = (uint64_t)(uintptr_t)(hb_w +
                    (size_t)(r0 + rg * 32 + row) * E_DIM + cs * 64 + seg * 8);
                asm volatile("global_store_dwordx4 %0, %1, off sc0 sc1"
                             :: "v"(dst), "v"(v) : "memory");
            }
        }

        if (s + 1 < nsteps) PEERS_BARRIER();
    }

    // ---- save c state for next dispatch ----
    #pragma unroll
    for (int rg = 0; rg < 2; ++rg)
        #pragma unroll
        for (int rf = 0; rf < 2; ++rf)
            #pragma unroll
            for (int rr = 0; rr < 4; ++rr)
                c_state[(size_t)(r0 + rg * 32 + rf * 16 + p * 4 + rr) * E_DIM + e] =
                    creg[rg][rf][rr];
#undef PEERS_BARRIER
#undef XZ_BASE
}

// ---------------------------------------------------------------------------
// Head MLP + L2 normalize (unchanged).
// ---------------------------------------------------------------------------
__global__ __launch_bounds__(256) void k_head(
    const float* __restrict__ xlast,
    const float* __restrict__ W0, const float* __restrict__ b0,
    const float* __restrict__ W1, const float* __restrict__ b1,
    float* __restrict__ out)
{
    const int n = blockIdx.x;
    const int j = threadIdx.x;

    __shared__ __align__(16) float xsh[E_DIM];
    __shared__ __align__(16) float y0[E_DIM];
    __shared__ float part[4];

    xsh[j] = xlast[(size_t)n * E_DIM + j];
    __syncthreads();

    float acc = b0[j];
    for (int k4 = 0; k4 < E_DIM; k4 += 4) {
        float4 xv = *reinterpret_cast<const float4*>(&xsh[k4]);
        #pragma unroll
        for (int kk = 0; kk < 4; ++kk)
            acc += (&xv.x)[kk] * W0[(size_t)(k4 + kk) * E_DIM + j];
    }
    y0[j] = fmaxf(acc, 0.f);
    __syncthreads();

    acc = b1[j];
    for (int k4 = 0; k4 < E_DIM; k4 += 4) {
        float4 yv = *reinterpret_cast<const float4*>(&y0[k4]);
        #pragma unroll
        for (int kk = 0; kk < 4; ++kk)
            acc += (&yv.x)[kk] * W1[(size_t)(k4 + kk) * E_DIM + j];
    }

    float sq = acc * acc;
    #pragma unroll
    for (int off = 32; off > 0; off >>= 1)
        sq += __shfl_xor(sq, off, 64);
    if ((j & 63) == 0) part[j >> 6] = sq;
    __syncthreads();
    float total = part[0] + part[1] + part[2] + part[3];

    out[(size_t)n * E_DIM + j] = acc * rsqrtf(total);
}

// ---------------------------------------------------------------------------
extern "C" void kernel_launch(void* const* d_in, const int* in_sizes, int n_in,
                              void* d_out, int out_size, void* d_ws, size_t ws_size,
                              hipStream_t stream) {
    const int*   code   = (const int*)  d_in[0];
    const float* aux    = (const float*)d_in[1];
    const int*   length = (const int*)  d_in[2];
    // d_in[3] = is_training (ignored)
    const float* W_lin  = (const float*)d_in[4];
    const float* b_lin  = (const float*)d_in[5];
    const float* K      = (const float*)d_in[6];
    const float* R      = (const float*)d_in[7];
    const float* b      = (const float*)d_in[8];
    const float* W0     = (const float*)d_in[9];
    const float* b0     = (const float*)d_in[10];
    const float* W1     = (const float*)d_in[11];
    const float* b1     = (const float*)d_in[12];
    float* out = (float*)d_out;

    // workspace layout (bytes, 16B aligned); total ~91.3 MB
    char* ws = (char*)d_ws;
    short* Wcoop   = (short*)(ws + 0);            //    524,288
    short* WfK     = (short*)(ws + 524288);       //    524,288
    short* WfL     = (short*)(ws + 1048576);      //    278,528
    float* xlast   = (float*)(ws + 1327104);      //  2,097,152
    float* c_state = (float*)(ws + 3424256);      //  2,097,152
    short* h_buf   = (short*)(ws + 5521408);      //  2,097,152 (2 parity bufs)
    int*   flags   = (int*)  (ws + 7618560);      //     12,288 (3 regions)
    short* xzp0    = (short*)(ws + 7630848);      // 41,943,040
    short* xzp1    = (short*)(ws + 49573888);     // 41,943,040

    k_zero      <<<12,  256, 0, stream>>>(flags);
    k_prep_wcoop<<<128, 256, 0, stream>>>(R, Wcoop);
    k_prep_wfk  <<<128, 256, 0, stream>>>(K, WfK);
    k_prep_wfl  <<<68,  256, 0, stream>>>(W_lin, WfL);

    // fused(c) writes xzp[c&1]; rcoop merges chunk pairs.
    k_fused<<<NFUSED, 512, 0, stream>>>(code, aux, WfL, b_lin, WfK, xzp0, 0);
    k_fused<<<NFUSED, 512, 0, stream>>>(code, aux, WfL, b_lin, WfK, xzp1, 10);
    k_rcoop<<<128, 256, 0, stream>>>(xzp0, xzp1, length, Wcoop, b, h_buf,
                                     c_state, xlast, flags + 0 * 1024, 0, 20);
    k_fused<<<NFUSED, 512, 0, stream>>>(code, aux, WfL, b_lin, WfK, xzp0, 20);
    k_fused<<<NFUSED, 512, 0, stream>>>(code, aux, WfL, b_lin, WfK, xzp1, 30);
    k_rcoop<<<128, 256, 0, stream>>>(xzp0, xzp1, length, Wcoop, b, h_buf,
                                     c_state, xlast, flags + 1 * 1024, 20, 20);
    k_fused<<<NFUSED, 512, 0, stream>>>(code, aux, WfL, b_lin, WfK, xzp0, 40);
    k_rcoop<<<128, 256, 0, stream>>>(xzp0, xzp1, length, Wcoop, b, h_buf,
                                     c_state, xlast, flags + 2 * 1024, 40, 10);

    k_head<<<N_BATCH, 256, 0, stream>>>(xlast, W0, b0, W1, b1, out);
}

// Round 23
// 452.407 us; speedup vs baseline: 1.2884x; 1.2884x over previous
//
#include <hip/hip_runtime.h>
#include <hip/hip_bf16.h>
#include <math.h>
#include <stdint.h>

#define N_BATCH 2048
#define T_STEPS 50
#define NCODES  40
#define MH      526
#define AUXD    10
#define WLROWS  536    // MH + AUXD
#define E_DIM   256
#define G_DIM   1024   // 4*E
#define TCHUNK  10     // time steps per fused chunk (5 chunks)
#define FROWS   128    // (n) rows per fused block
#define NFUSED  (TCHUNK * 16)   // 160 fused blocks per chunk

typedef __attribute__((ext_vector_type(8))) short short8;   // 8 bf16 = 4 VGPR
typedef __attribute__((ext_vector_type(4))) short short4v;  // 4 bf16 = 2 VGPR
typedef __attribute__((ext_vector_type(4))) float f32x4;
typedef __attribute__((ext_vector_type(4))) int   i32x4;    // asm-safe 16B

__device__ __forceinline__ short f2bf(float f) {
    __hip_bfloat16 h = __float2bfloat16(f);
    return *reinterpret_cast<short*>(&h);
}
__device__ __forceinline__ float bf2f(unsigned short u) {
    return __uint_as_float(((unsigned int)u) << 16);
}
__device__ __forceinline__ float sigf(float x) {
    return 1.f / (1.f + __expf(-x));
}
__device__ __forceinline__ float tanhfast(float x) {
    return 2.f / (1.f + __expf(-2.f * x)) - 1.f;
}

// ---------------------------------------------------------------------------
// Zero peer-barrier slots: 3 regions x 64 rgs x 32-int stride (128B lines).
// ---------------------------------------------------------------------------
__global__ __launch_bounds__(256) void k_zero(int* __restrict__ cnt)
{
    const int i = blockIdx.x * 256 + threadIdx.x;
    if (i < 3 * 64 * 32) cnt[i] = 0;
}

// ---------------------------------------------------------------------------
// Wcoop: R pre-permuted for rcoop register residency.
// fg = ((cs*4 + w)*4 + g)*8 + kk ; Wcoop[fg*512 + lane*8 + j]
//   = R[kk*32 + p*8 + j][g*256 + cs*64 + w*16 + lr]
// ---------------------------------------------------------------------------
__global__ __launch_bounds__(256) void k_prep_wcoop(
    const float* __restrict__ R, short* __restrict__ Wcoop)
{
    const int gid  = blockIdx.x * 256 + threadIdx.x;   // 32768
    const int fg   = gid >> 6, lane = gid & 63;
    const int p    = lane >> 4, lr = lane & 15;
    const int kk   = fg & 7;
    const int g    = (fg >> 3) & 3;
    const int w    = (fg >> 5) & 3;
    const int cs   = fg >> 7;
    const int n    = g * 256 + cs * 64 + w * 16 + lr;
    short* dst = Wcoop + (size_t)fg * 512 + lane * 8;
    #pragma unroll
    for (int j = 0; j < 8; ++j)
        dst[j] = f2bf(R[(size_t)(kk * 32 + p * 8 + j) * G_DIM + n]);
}

// WfK (K for fused phase 3): fg = (kb*8 + cb)*8 + w
__global__ __launch_bounds__(256) void k_prep_wfk(
    const float* __restrict__ K, short* __restrict__ WfK)
{
    const int gid  = blockIdx.x * 256 + threadIdx.x;   // 32768
    const int fg   = gid >> 6, lane = gid & 63;
    const int p    = lane >> 4, lr = lane & 15;
    const int kb   = fg >> 6;
    const int cb   = (fg >> 3) & 7;
    const int w    = fg & 7;
    const int n    = w * 128 + cb * 16 + lr;
    short* dst = WfK + (size_t)fg * 512 + lane * 8;
    #pragma unroll
    for (int j = 0; j < 8; ++j)
        dst[j] = f2bf(K[(size_t)(kb * 32 + p * 8 + j) * G_DIM + n]);
}

// WfL (W_lin for fused phase 2): fg = (kk*2 + cb)*8 + w, kk 0..16
__global__ __launch_bounds__(256) void k_prep_wfl(
    const float* __restrict__ W_lin, short* __restrict__ WfL)
{
    const int gid  = blockIdx.x * 256 + threadIdx.x;   // 17408
    const int fg   = gid >> 6, lane = gid & 63;
    const int p    = lane >> 4, lr = lane & 15;
    const int kk   = fg >> 4;
    const int cb   = (fg >> 3) & 1;
    const int w    = fg & 7;
    const int n    = w * 32 + cb * 16 + lr;
    short* dst = WfL + (size_t)fg * 512 + lane * 8;
    #pragma unroll
    for (int j = 0; j < 8; ++j) {
        const int k = kk * 32 + p * 8 + j;
        dst[j] = (k < WLROWS) ? f2bf(W_lin[(size_t)k * E_DIM + n]) : (short)0;
    }
}

// ---------------------------------------------------------------------------
// Fused v2: 128 rows/block (2x weight reuse -> half the L3 weight stream).
// Phase 2 stages the one-hot in two K-halves (9+8 kk-groups, 128x288 LDS)
// with the accumulator persisting across halves. Phase 3 as before with
// rb=8. Output in rcoop fragment order (rgg = ngg*8 + rb).
// ---------------------------------------------------------------------------
__global__ __launch_bounds__(512, 1) void k_fused(
    const int* __restrict__ code, const float* __restrict__ aux,
    const short* __restrict__ WfL, const float* __restrict__ b_lin,
    const short* __restrict__ WfK, short* __restrict__ xzp, int t0f)
{
    const int tid  = threadIdx.x;
    const int w    = tid >> 6;
    const int lane = tid & 63;
    const int lr   = lane & 15;
    const int p    = lane >> 4;
    const int fid  = blockIdx.x;
    const int tl   = fid >> 4;                 // 0..TCHUNK-1
    const int ngg  = fid & 15;
    const int n0   = ngg * FROWS;              // 128 consecutive batch rows
    const int t    = t0f + tl;

    __shared__ __align__(16) short oh[FROWS][288];   // 73728 B (one K-half)
    __shared__ __align__(16) short xs[FROWS][264];   // 67584 B

    // ---- Phase 2: xs = relu(onehot @ WfL^T + b_lin), K staged in 2 halves ----
    f32x4 acc2[8][2];
    #pragma unroll
    for (int rb = 0; rb < 8; ++rb)
        #pragma unroll
        for (int cb = 0; cb < 2; ++cb)
            acc2[rb][cb] = (f32x4){0.f, 0.f, 0.f, 0.f};

    for (int kh = 0; kh < 2; ++kh) {
        const int c0  = kh ? 288 : 0;
        const int Wd  = kh ? 256 : 288;
        const int nk  = kh ? 8 : 9;
        const int kk0 = kh ? 9 : 0;

        // zero one-hot half
        for (int i = tid; i < (FROWS * 288) / 8; i += 512)
            ((int4*)&oh[0][0])[i] = (int4){0, 0, 0, 0};
        __syncthreads();

        // scatter codes in range (presence; duplicates idempotent; drop c==0)
        for (int i = tid; i < FROWS * NCODES; i += 512) {
            const int r = i / NCODES;
            const int j = i - r * NCODES;
            const int c = code[((size_t)(n0 + r) * T_STEPS + t) * NCODES + j];
            const int cm1 = c - 1;
            if (c > 0 && cm1 >= c0 && cm1 < c0 + Wd)
                oh[r][cm1 - c0] = 0x3F80;
        }
        if (kh == 1) {
            for (int i = tid; i < FROWS * AUXD; i += 512) {
                const int r = i / AUXD;
                const int a = i - r * AUXD;
                oh[r][MH - 288 + a] =
                    f2bf(aux[((size_t)(n0 + r) * T_STEPS + t) * AUXD + a]);
            }
        }
        __syncthreads();

        for (int kx = 0; kx < nk; ++kx) {
            short8 a[8];
            #pragma unroll
            for (int rb = 0; rb < 8; ++rb)
                a[rb] = *(const short8*)&oh[rb * 16 + lr][kx * 32 + p * 8];
            #pragma unroll
            for (int cb = 0; cb < 2; ++cb) {
                short8 bf = *(const short8*)(WfL +
                    (size_t)(((kk0 + kx) * 2 + cb) * 8 + w) * 512 + lane * 8);
                #pragma unroll
                for (int rb = 0; rb < 8; ++rb)
                    acc2[rb][cb] = __builtin_amdgcn_mfma_f32_16x16x32_bf16(
                        a[rb], bf, acc2[rb][cb], 0, 0, 0);
            }
        }
        __syncthreads();   // oh reads done before next half's re-zero
    }

    {
        float bias[2];
        #pragma unroll
        for (int cb = 0; cb < 2; ++cb) bias[cb] = b_lin[w * 32 + cb * 16 + lr];
        #pragma unroll
        for (int rb = 0; rb < 8; ++rb)
            #pragma unroll
            for (int cb = 0; cb < 2; ++cb)
                #pragma unroll
                for (int rr = 0; rr < 4; ++rr)
                    xs[rb * 16 + p * 4 + rr][w * 32 + cb * 16 + lr] =
                        f2bf(fmaxf(acc2[rb][cb][rr] + bias[cb], 0.f));
        __syncthreads();
    }

    // ---- Phase 3: xz = xs @ WfK^T, two cb-halves, frag-order output ----
    const short* wfk_thr = WfK + (size_t)w * 512 + lane * 8;
    #pragma unroll
    for (int half = 0; half < 2; ++half) {
        f32x4 acc[8][4];
        #pragma unroll
        for (int rb = 0; rb < 8; ++rb)
            #pragma unroll
            for (int c4 = 0; c4 < 4; ++c4)
                acc[rb][c4] = (f32x4){0.f, 0.f, 0.f, 0.f};

        for (int kb = 0; kb < 8; ++kb) {
            short8 a[8];
            #pragma unroll
            for (int rb = 0; rb < 8; ++rb)
                a[rb] = *(const short8*)&xs[rb * 16 + lr][kb * 32 + p * 8];
            #pragma unroll
            for (int c4 = 0; c4 < 4; ++c4) {
                const int cb = half * 4 + c4;
                short8 bf = *(const short8*)(wfk_thr + (size_t)(kb * 8 + cb) * 4096);
                #pragma unroll
                for (int rb = 0; rb < 8; ++rb)
                    acc[rb][c4] = __builtin_amdgcn_mfma_f32_16x16x32_bf16(
                        a[rb], bf, acc[rb][c4], 0, 0, 0);
            }
        }
        #pragma unroll
        for (int rb = 0; rb < 8; ++rb) {
            const int rgg = ngg * 8 + rb;   // global 16-row group
            #pragma unroll
            for (int c4 = 0; c4 < 4; ++c4) {
                const int cb = half * 4 + c4;
                const int c0 = w * 128 + cb * 16;
                const int g  = c0 >> 8;
                const int wp = (c0 >> 5) & 7;
                const int eb = (c0 >> 4) & 1;
                const int j8 = eb * 4 + g;
                short4v v;
                #pragma unroll
                for (int rr = 0; rr < 4; ++rr) v[rr] = f2bf(acc[rb][c4][rr]);
                *(short4v*)(xzp +
                    (((size_t)rgg * TCHUNK + tl) * 64 + wp * 8 + j8) * 256 +
                    lane * 4) = v;
            }
        }
    }
}

// ---------------------------------------------------------------------------
// Recurrence v14 (R21, best-validated): per step, block coop-loads its
// 32-row h ONCE (coalesced sc0sc1, 16 KB) into ^kk-swizzled frag-major LDS,
// all 4 waves ds_read_b128 a-frags. Weights register-resident; slot barrier;
// parity h_buf.
// ---------------------------------------------------------------------------
__global__ __launch_bounds__(256, 1) void k_rcoop(
    const short* __restrict__ xz0, const short* __restrict__ xz1,
    const int* __restrict__ length,
    const short* __restrict__ Wcoop, const float* __restrict__ b,
    short* __restrict__ h_buf, float* __restrict__ c_state,
    float* __restrict__ xlast, int* __restrict__ flags,
    int t0, int nsteps)
{
    const int tid  = threadIdx.x;
    const int w    = tid >> 6;          // 0..3
    const int lane = tid & 63;
    const int lr   = lane & 15;
    const int p    = lane >> 4;
    const int cs   = blockIdx.x >> 6;   // 0..3
    const int rg   = blockIdx.x & 63;   // 0..63 (32-row group)
    const int r0   = rg * 32;
    const int e    = cs * 64 + w * 16 + lr;

    __shared__ __align__(16) short h_f[2][8][512];   // swizzled frag-major, 16KB
    __shared__ __align__(16) short h_o[32][64];      // own-slice staging, 4KB
    __shared__ int s_len[32];
    if (tid < 32) s_len[tid] = length[r0 + tid];

    // ---- R slice -> registers (resident across all steps) ----
    short8 bw[4][8];
    {
        const short* wb = Wcoop + ((size_t)((cs * 4 + w) * 4)) * 8 * 512 + lane * 8;
        #pragma unroll
        for (int g = 0; g < 4; ++g)
            #pragma unroll
            for (int kk = 0; kk < 8; ++kk)
                bw[g][kk] = *(const short8*)(wb + (size_t)(g * 8 + kk) * 512);
    }

    float bias[4];
    #pragma unroll
    for (int g = 0; g < 4; ++g) bias[g] = b[g * 256 + e];

    float creg[2][4];
    if (t0 == 0) {
        #pragma unroll
        for (int rf = 0; rf < 2; ++rf)
            #pragma unroll
            for (int rr = 0; rr < 4; ++rr) creg[rf][rr] = 0.f;
    } else {
        #pragma unroll
        for (int rf = 0; rf < 2; ++rf)
            #pragma unroll
            for (int rr = 0; rr < 4; ++rr)
                creg[rf][rr] = c_state[(size_t)(r0 + rf * 16 + p * 4 + rr) * E_DIM + e];
    }
    __syncthreads();

    int len_r[2][4];
    #pragma unroll
    for (int rf = 0; rf < 2; ++rf)
        #pragma unroll
        for (int rr = 0; rr < 4; ++rr)
            len_r[rf][rr] = s_len[rf * 16 + p * 4 + rr];

    const uint64_t slot_addr = (uint64_t)(uintptr_t)(flags + rg * 32 + cs);
    const uint64_t line_addr = (uint64_t)(uintptr_t)(flags + rg * 32);
    int bcnt = 0;

#define PEERS_BARRIER()                                                        \
    do {                                                                       \
        ++bcnt;                                                                \
        __syncthreads(); /* drains vmcnt: sc h-stores complete */              \
        if (tid == 0) {                                                        \
            asm volatile("global_store_dword %0, %1, off sc0 sc1"              \
                         :: "v"(slot_addr), "v"(bcnt) : "memory");             \
            i32x4 fv;                                                          \
            do {                                                               \
                asm volatile("global_load_dwordx4 %0, %1, off sc0 sc1\n\t"     \
                             "s_waitcnt vmcnt(0)"                              \
                             : "=v"(fv) : "v"(line_addr) : "memory");          \
            } while (fv[0] < bcnt || fv[1] < bcnt ||                           \
                     fv[2] < bcnt || fv[3] < bcnt);                            \
        }                                                                      \
        __syncthreads();                                                       \
    } while (0)

    // ---- chunk-0 init: zero own slice of h_buf parity 0 ----
    if (t0 == 0) {
        const i32x4 z4 = {0, 0, 0, 0};
        const int row = tid >> 3, seg = tid & 7;   // 32 rows x 8 segs
        const uint64_t dst = (uint64_t)(uintptr_t)(h_buf +
            (size_t)(r0 + row) * E_DIM + cs * 64 + seg * 8);
        asm volatile("global_store_dwordx4 %0, %1, off sc0 sc1"
                     :: "v"(dst), "v"(z4) : "memory");
        PEERS_BARRIER();
    }

    // hoisted invariants
    const short* hb0 = h_buf;
    const short* hb1 = h_buf + (size_t)N_BATCH * E_DIM;
    const size_t coloff = (size_t)((cs * 2 + (w >> 1)) * 8 + (w & 1) * 4) * 256 +
                          lane * 4;   // + g*256 per gate
    const size_t rowoff0 = (size_t)(2 * rg + 0) * TCHUNK * 16384;
    const size_t rowoff1 = (size_t)(2 * rg + 1) * TCHUNK * 16384;

#define XZ_BASE(T, RFOFF)                                                      \
    ((((((T) / TCHUNK) & 1) ? xz1 : xz0)) + (RFOFF) +                          \
     (size_t)((T) % TCHUNK) * 16384 + coloff)

    // ---- prefetch xz for first step ----
    short4v xv[2][4];
    {
        const short* b0p = XZ_BASE(t0, rowoff0);
        const short* b1p = XZ_BASE(t0, rowoff1);
        #pragma unroll
        for (int g = 0; g < 4; ++g) {
            xv[0][g] = *(const short4v*)(b0p + g * 256);
            xv[1][g] = *(const short4v*)(b1p + g * 256);
        }
    }

    // this thread's coop-load geometry (4 chunks, coalesced)
    const int ld_row = tid >> 5;           // base rows: tid>>5 + it*8
    const int ld_ch  = tid & 31;
    const int ld_kk  = ld_ch >> 2;

    for (int s = 0; s < nsteps; ++s) {
        const int t = t0 + s;
        const short* hb_r = (t & 1) ? hb1 : hb0;

        // ---- stage h(t): coalesced sc0sc1 load -> swizzled LDS ----
        {
            short8 ld[4];
            #pragma unroll
            for (int it = 0; it < 4; ++it) {
                const int row = ld_row + it * 8;
                const uint64_t src = (uint64_t)(uintptr_t)(hb_r +
                    (size_t)(r0 + row) * E_DIM + ld_ch * 8);
                asm volatile("global_load_dwordx4 %0, %1, off sc0 sc1"
                             : "=&v"(ld[it]) : "v"(src) : "memory");
            }
            asm volatile("s_waitcnt vmcnt(0)" ::: "memory");
            #pragma unroll
            for (int it = 0; it < 4; ++it) {
                const int row  = ld_row + it * 8;
                const int slot = (((ld_ch & 3) * 16) + (row & 15)) ^ ld_kk;
                *(short8*)&h_f[row >> 4][ld_kk][slot * 8] = ld[it];
            }
        }
        __syncthreads();

        // acc init from prefetched xz (registers)
        f32x4 acc[2][4];
        #pragma unroll
        for (int rf = 0; rf < 2; ++rf)
            #pragma unroll
            for (int g = 0; g < 4; ++g)
                #pragma unroll
                for (int rr = 0; rr < 4; ++rr)
                    acc[rf][g][rr] = bf2f((unsigned short)xv[rf][g][rr]);

        // ---- h @ R : a-frags from swizzled LDS, weights from registers ----
        #pragma unroll
        for (int kk = 0; kk < 8; ++kk) {
            const int sl = (lane ^ kk) * 8;
            short8 a0 = *(const short8*)&h_f[0][kk][sl];
            short8 a1 = *(const short8*)&h_f[1][kk][sl];
            #pragma unroll
            for (int g = 0; g < 4; ++g) {
                acc[0][g] = __builtin_amdgcn_mfma_f32_16x16x32_bf16(
                    a0, bw[g][kk], acc[0][g], 0, 0, 0);
                acc[1][g] = __builtin_amdgcn_mfma_f32_16x16x32_bf16(
                    a1, bw[g][kk], acc[1][g], 0, 0, 0);
            }
        }

        // next-step xz prefetch (may cross chunk parity)
        if (s + 1 < nsteps) {
            const short* b0p = XZ_BASE(t + 1, rowoff0);
            const short* b1p = XZ_BASE(t + 1, rowoff1);
            #pragma unroll
            for (int g = 0; g < 4; ++g) {
                xv[0][g] = *(const short4v*)(b0p + g * 256);
                xv[1][g] = *(const short4v*)(b1p + g * 256);
            }
        }

        // ---- gates in registers; stage h slice into LDS ----
        #pragma unroll
        for (int rf = 0; rf < 2; ++rf) {
            #pragma unroll
            for (int rr = 0; rr < 4; ++rr) {
                float zi = acc[rf][0][rr] + bias[0];
                float zf = acc[rf][1][rr] + bias[1];
                float zg = acc[rf][2][rr] + bias[2];
                float zo = acc[rf][3][rr] + bias[3];
                float ig = sigf(zi), fg = sigf(zf);
                float gg = tanhfast(zg), og = sigf(zo);
                float cc = fg * creg[rf][rr] + ig * gg;
                float hh = og * tanhfast(cc);
                creg[rf][rr] = cc;
                h_o[rf * 16 + p * 4 + rr][w * 16 + lr] = f2bf(hh);
                const int row = r0 + rf * 16 + p * 4 + rr;
                if (t == len_r[rf][rr] - 1)
                    xlast[(size_t)row * E_DIM + e] = hh;
            }
        }
        __syncthreads();   // h_o complete (also guards h_f reuse next step)

        // ---- coalesced sc0sc1 store of own h(t+1) slice ----
        {
            short* hb_w = (short*)(((t + 1) & 1) ? hb1 : hb0);
            const int row = tid >> 3, seg = tid & 7;
            i32x4 v = *(const i32x4*)&h_o[row][seg * 8];
            const uint64_t dst = (uint64_t)(uintptr_t)(hb_w +
                (size_t)(r0 + row) * E_DIM + cs * 64 + seg * 8);
            asm volatile("global_store_dwordx4 %0, %1, off sc0 sc1"
                         :: "v"(dst), "v"(v) : "memory");
        }

        if (s + 1 < nsteps) PEERS_BARRIER();
    }

    // ---- save c state for next dispatch ----
    #pragma unroll
    for (int rf = 0; rf < 2; ++rf)
        #pragma unroll
        for (int rr = 0; rr < 4; ++rr)
            c_state[(size_t)(r0 + rf * 16 + p * 4 + rr) * E_DIM + e] = creg[rf][rr];
#undef PEERS_BARRIER
#undef XZ_BASE
}

// ---------------------------------------------------------------------------
// Head MLP + L2 normalize (unchanged).
// ---------------------------------------------------------------------------
__global__ __launch_bounds__(256) void k_head(
    const float* __restrict__ xlast,
    const float* __restrict__ W0, const float* __restrict__ b0,
    const float* __restrict__ W1, const float* __restrict__ b1,
    float* __restrict__ out)
{
    const int n = blockIdx.x;
    const int j = threadIdx.x;

    __shared__ __align__(16) float xsh[E_DIM];
    __shared__ __align__(16) float y0[E_DIM];
    __shared__ float part[4];

    xsh[j] = xlast[(size_t)n * E_DIM + j];
    __syncthreads();

    float acc = b0[j];
    for (int k4 = 0; k4 < E_DIM; k4 += 4) {
        float4 xv = *reinterpret_cast<const float4*>(&xsh[k4]);
        #pragma unroll
        for (int kk = 0; kk < 4; ++kk)
            acc += (&xv.x)[kk] * W0[(size_t)(k4 + kk) * E_DIM + j];
    }
    y0[j] = fmaxf(acc, 0.f);
    __syncthreads();

    acc = b1[j];
    for (int k4 = 0; k4 < E_DIM; k4 += 4) {
        float4 yv = *reinterpret_cast<const float4*>(&y0[k4]);
        #pragma unroll
        for (int kk = 0; kk < 4; ++kk)
            acc += (&yv.x)[kk] * W1[(size_t)(k4 + kk) * E_DIM + j];
    }

    float sq = acc * acc;
    #pragma unroll
    for (int off = 32; off > 0; off >>= 1)
        sq += __shfl_xor(sq, off, 64);
    if ((j & 63) == 0) part[j >> 6] = sq;
    __syncthreads();
    float total = part[0] + part[1] + part[2] + part[3];

    out[(size_t)n * E_DIM + j] = acc * rsqrtf(total);
}

// ---------------------------------------------------------------------------
extern "C" void kernel_launch(void* const* d_in, const int* in_sizes, int n_in,
                              void* d_out, int out_size, void* d_ws, size_t ws_size,
                              hipStream_t stream) {
    const int*   code   = (const int*)  d_in[0];
    const float* aux    = (const float*)d_in[1];
    const int*   length = (const int*)  d_in[2];
    // d_in[3] = is_training (ignored)
    const float* W_lin  = (const float*)d_in[4];
    const float* b_lin  = (const float*)d_in[5];
    const float* K      = (const float*)d_in[6];
    const float* R      = (const float*)d_in[7];
    const float* b      = (const float*)d_in[8];
    const float* W0     = (const float*)d_in[9];
    const float* b0     = (const float*)d_in[10];
    const float* W1     = (const float*)d_in[11];
    const float* b1     = (const float*)d_in[12];
    float* out = (float*)d_out;

    // workspace layout (bytes, 16B aligned); total ~91.3 MB
    char* ws = (char*)d_ws;
    short* Wcoop   = (short*)(ws + 0);            //    524,288
    short* WfK     = (short*)(ws + 524288);       //    524,288
    short* WfL     = (short*)(ws + 1048576);      //    278,528
    float* xlast   = (float*)(ws + 1327104);      //  2,097,152
    float* c_state = (float*)(ws + 3424256);      //  2,097,152
    short* h_buf   = (short*)(ws + 5521408);      //  2,097,152 (2 parity bufs)
    int*   flags   = (int*)  (ws + 7618560);      //     24,576 (3 regions)
    short* xzp0    = (short*)(ws + 7643136);      // 41,943,040
    short* xzp1    = (short*)(ws + 49586176);     // 41,943,040

    k_zero      <<<24,  256, 0, stream>>>(flags);
    k_prep_wcoop<<<128, 256, 0, stream>>>(R, Wcoop);
    k_prep_wfk  <<<128, 256, 0, stream>>>(K, WfK);
    k_prep_wfl  <<<68,  256, 0, stream>>>(W_lin, WfL);

    // fused(c) writes xzp[c&1]; rcoop merges chunk pairs.
    k_fused<<<NFUSED, 512, 0, stream>>>(code, aux, WfL, b_lin, WfK, xzp0, 0);
    k_fused<<<NFUSED, 512, 0, stream>>>(code, aux, WfL, b_lin, WfK, xzp1, 10);
    k_rcoop<<<256, 256, 0, stream>>>(xzp0, xzp1, length, Wcoop, b, h_buf,
                                     c_state, xlast, flags + 0 * 2048, 0, 20);
    k_fused<<<NFUSED, 512, 0, stream>>>(code, aux, WfL, b_lin, WfK, xzp0, 20);
    k_fused<<<NFUSED, 512, 0, stream>>>(code, aux, WfL, b_lin, WfK, xzp1, 30);
    k_rcoop<<<256, 256, 0, stream>>>(xzp0, xzp1, length, Wcoop, b, h_buf,
                                     c_state, xlast, flags + 1 * 2048, 20, 20);
    k_fused<<<NFUSED, 512, 0, stream>>>(code, aux, WfL, b_lin, WfK, xzp0, 40);
    k_rcoop<<<256, 256, 0, stream>>>(xzp0, xzp1, length, Wcoop, b, h_buf,
                                     c_state, xlast, flags + 2 * 2048, 40, 10);

    k_head<<<N_BATCH, 256, 0, stream>>>(xlast, W0, b0, W1, b1, out);
}

// Round 24
// 425.029 us; speedup vs baseline: 1.3714x; 1.0644x over previous
//
#include <hip/hip_runtime.h>
#include <hip/hip_bf16.h>
#include <math.h>
#include <stdint.h>

#define N_BATCH 2048
#define T_STEPS 50
#define NCODES  40
#define MH      526
#define AUXD    10
#define WLROWS  536    // MH + AUXD
#define E_DIM   256
#define G_DIM   1024   // 4*E
#define TCHUNK  10     // time steps per fused chunk (5 chunks)
#define MBLK    64     // (n,t) rows per fused block
#define NFUSED  (TCHUNK * 32)   // 320 fused blocks per chunk

typedef __attribute__((ext_vector_type(8))) short short8;   // 8 bf16 = 4 VGPR
typedef __attribute__((ext_vector_type(4))) short short4v;  // 4 bf16 = 2 VGPR
typedef __attribute__((ext_vector_type(4))) float f32x4;
typedef __attribute__((ext_vector_type(4))) int   i32x4;    // asm-safe 16B

__device__ __forceinline__ short f2bf(float f) {
    __hip_bfloat16 h = __float2bfloat16(f);
    return *reinterpret_cast<short*>(&h);
}
__device__ __forceinline__ float bf2f(unsigned short u) {
    return __uint_as_float(((unsigned int)u) << 16);
}
__device__ __forceinline__ float sigf(float x) {
    return 1.f / (1.f + __expf(-x));
}
__device__ __forceinline__ float tanhfast(float x) {
    return 2.f / (1.f + __expf(-2.f * x)) - 1.f;
}

// ---------------------------------------------------------------------------
// Zero peer-barrier slots: 3 regions x 64 rgs x 32-int stride (128B lines).
// ---------------------------------------------------------------------------
__global__ __launch_bounds__(256) void k_zero(int* __restrict__ cnt)
{
    const int i = blockIdx.x * 256 + threadIdx.x;
    if (i < 3 * 64 * 32) cnt[i] = 0;
}

// ---------------------------------------------------------------------------
// Wcoop: R pre-permuted for rcoop register residency.
// fg = ((cs*4 + w)*4 + g)*8 + kk ; Wcoop[fg*512 + lane*8 + j]
//   = R[kk*32 + p*8 + j][g*256 + cs*64 + w*16 + lr]
// ---------------------------------------------------------------------------
__global__ __launch_bounds__(256) void k_prep_wcoop(
    const float* __restrict__ R, short* __restrict__ Wcoop)
{
    const int gid  = blockIdx.x * 256 + threadIdx.x;   // 32768
    const int fg   = gid >> 6, lane = gid & 63;
    const int p    = lane >> 4, lr = lane & 15;
    const int kk   = fg & 7;
    const int g    = (fg >> 3) & 3;
    const int w    = (fg >> 5) & 3;
    const int cs   = fg >> 7;
    const int n    = g * 256 + cs * 64 + w * 16 + lr;
    short* dst = Wcoop + (size_t)fg * 512 + lane * 8;
    #pragma unroll
    for (int j = 0; j < 8; ++j)
        dst[j] = f2bf(R[(size_t)(kk * 32 + p * 8 + j) * G_DIM + n]);
}

// WfK (K for fused phase 3): fg = (kb*8 + cb)*8 + w
__global__ __launch_bounds__(256) void k_prep_wfk(
    const float* __restrict__ K, short* __restrict__ WfK)
{
    const int gid  = blockIdx.x * 256 + threadIdx.x;   // 32768
    const int fg   = gid >> 6, lane = gid & 63;
    const int p    = lane >> 4, lr = lane & 15;
    const int kb   = fg >> 6;
    const int cb   = (fg >> 3) & 7;
    const int w    = fg & 7;
    const int n    = w * 128 + cb * 16 + lr;
    short* dst = WfK + (size_t)fg * 512 + lane * 8;
    #pragma unroll
    for (int j = 0; j < 8; ++j)
        dst[j] = f2bf(K[(size_t)(kb * 32 + p * 8 + j) * G_DIM + n]);
}

// WfL (W_lin for fused phase 2): fg = (kk*2 + cb)*8 + w, kk 0..16
__global__ __launch_bounds__(256) void k_prep_wfl(
    const float* __restrict__ W_lin, short* __restrict__ WfL)
{
    const int gid  = blockIdx.x * 256 + threadIdx.x;   // 17408
    const int fg   = gid >> 6, lane = gid & 63;
    const int p    = lane >> 4, lr = lane & 15;
    const int kk   = fg >> 4;
    const int cb   = (fg >> 3) & 1;
    const int w    = fg & 7;
    const int n    = w * 32 + cb * 16 + lr;
    short* dst = WfL + (size_t)fg * 512 + lane * 8;
    #pragma unroll
    for (int j = 0; j < 8; ++j) {
        const int k = kk * 32 + p * 8 + j;
        dst[j] = (k < WLROWS) ? f2bf(W_lin[(size_t)k * E_DIM + n]) : (short)0;
    }
}

// ---------------------------------------------------------------------------
// Fused embed + xz GEMM (R16-validated body, unchanged).
// ---------------------------------------------------------------------------
__global__ __launch_bounds__(512, 1) void k_fused(
    const int* __restrict__ code, const float* __restrict__ aux,
    const short* __restrict__ WfL, const float* __restrict__ b_lin,
    const short* __restrict__ WfK, short* __restrict__ xzp, int t0f)
{
    const int tid  = threadIdx.x;
    const int w    = tid >> 6;
    const int lane = tid & 63;
    const int lr   = lane & 15;
    const int p    = lane >> 4;
    const int fid  = blockIdx.x;
    const int tl   = fid >> 5;                 // 0..TCHUNK-1
    const int ngg  = fid & 31;
    const int n0   = ngg * MBLK;               // 64 consecutive batch rows
    const int t    = t0f + tl;
    const int ph8  = (fid >> 3) & 7;
    const int ph17 = (fid >> 3) % 17;

    __shared__ __align__(16) short oh[MBLK][552];   // 70656 B
    __shared__ __align__(16) short xs[MBLK][264];   // 33792 B

    for (int i = tid; i < (MBLK * 552) / 8; i += 512)
        ((int4*)&oh[0][0])[i] = (int4){0, 0, 0, 0};
    __syncthreads();

    for (int i = tid; i < MBLK * NCODES; i += 512) {
        const int r = i / NCODES;
        const int j = i - r * NCODES;
        const int c = code[((size_t)(n0 + r) * T_STEPS + t) * NCODES + j];
        if (c > 0) ((unsigned short*)&oh[0][0])[r * 552 + (c - 1)] = 0x3F80;
    }
    for (int i = tid; i < MBLK * AUXD; i += 512) {
        const int r = i / AUXD;
        const int a = i - r * AUXD;
        oh[r][MH + a] = f2bf(aux[((size_t)(n0 + r) * T_STEPS + t) * AUXD + a]);
    }
    __syncthreads();

    const short* wfl_thr = WfL + (size_t)w * 512 + lane * 8;
    const short* wfk_thr = WfK + (size_t)w * 512 + lane * 8;

    // ---- Phase 2: xs = relu(oh @ WfL^T + b_lin) ----
    {
        f32x4 acc[4][2];
        #pragma unroll
        for (int rb = 0; rb < 4; ++rb)
            #pragma unroll
            for (int cb = 0; cb < 2; ++cb)
                acc[rb][cb] = (f32x4){0.f, 0.f, 0.f, 0.f};

        for (int kk = 0; kk < 17; ++kk) {
            int kx = kk + ph17; if (kx >= 17) kx -= 17;
            short8 a[4];
            #pragma unroll
            for (int rb = 0; rb < 4; ++rb)
                a[rb] = *(const short8*)&oh[rb * 16 + lr][kx * 32 + p * 8];
            #pragma unroll
            for (int cb = 0; cb < 2; ++cb) {
                short8 bf = *(const short8*)(wfl_thr + (size_t)(kx * 2 + cb) * 4096);
                #pragma unroll
                for (int rb = 0; rb < 4; ++rb)
                    acc[rb][cb] = __builtin_amdgcn_mfma_f32_16x16x32_bf16(
                        a[rb], bf, acc[rb][cb], 0, 0, 0);
            }
        }
        float bias[2];
        #pragma unroll
        for (int cb = 0; cb < 2; ++cb) bias[cb] = b_lin[w * 32 + cb * 16 + lr];
        #pragma unroll
        for (int rb = 0; rb < 4; ++rb)
            #pragma unroll
            for (int cb = 0; cb < 2; ++cb)
                #pragma unroll
                for (int rr = 0; rr < 4; ++rr)
                    xs[rb * 16 + p * 4 + rr][w * 32 + cb * 16 + lr] =
                        f2bf(fmaxf(acc[rb][cb][rr] + bias[cb], 0.f));
        __syncthreads();
    }

    // ---- Phase 3: xz = xs @ WfK^T, frag-order output ----
    #pragma unroll
    for (int half = 0; half < 2; ++half) {
        f32x4 acc[4][4];
        #pragma unroll
        for (int rb = 0; rb < 4; ++rb)
            #pragma unroll
            for (int c4 = 0; c4 < 4; ++c4)
                acc[rb][c4] = (f32x4){0.f, 0.f, 0.f, 0.f};

        for (int kb = 0; kb < 8; ++kb) {
            const int kx = (kb + ph8) & 7;
            short8 a[4];
            #pragma unroll
            for (int rb = 0; rb < 4; ++rb)
                a[rb] = *(const short8*)&xs[rb * 16 + lr][kx * 32 + p * 8];
            #pragma unroll
            for (int c4 = 0; c4 < 4; ++c4) {
                const int cb = half * 4 + c4;
                short8 bf = *(const short8*)(wfk_thr + (size_t)(kx * 8 + cb) * 4096);
                #pragma unroll
                for (int rb = 0; rb < 4; ++rb)
                    acc[rb][c4] = __builtin_amdgcn_mfma_f32_16x16x32_bf16(
                        a[rb], bf, acc[rb][c4], 0, 0, 0);
            }
        }
        #pragma unroll
        for (int rb = 0; rb < 4; ++rb) {
            const int rgg = ngg * 4 + rb;   // global 16-row group
            #pragma unroll
            for (int c4 = 0; c4 < 4; ++c4) {
                const int cb = half * 4 + c4;
                const int c0 = w * 128 + cb * 16;
                const int g  = c0 >> 8;
                const int wp = (c0 >> 5) & 7;
                const int eb = (c0 >> 4) & 1;
                const int j8 = eb * 4 + g;
                short4v v;
                #pragma unroll
                for (int rr = 0; rr < 4; ++rr) v[rr] = f2bf(acc[rb][c4][rr]);
                *(short4v*)(xzp +
                    (((size_t)rgg * TCHUNK + tl) * 64 + wp * 8 + j8) * 256 +
                    lane * 4) = v;
            }
        }
    }
}

// ---------------------------------------------------------------------------
// Recurrence v14 (R21, best-validated): per step, block coop-loads its
// 32-row h ONCE (coalesced sc0sc1, 16 KB) into ^kk-swizzled frag-major LDS,
// all 4 waves ds_read_b128 a-frags. Weights register-resident; slot barrier;
// parity h_buf.
// ---------------------------------------------------------------------------
__global__ __launch_bounds__(256, 1) void k_rcoop(
    const short* __restrict__ xz0, const short* __restrict__ xz1,
    const int* __restrict__ length,
    const short* __restrict__ Wcoop, const float* __restrict__ b,
    short* __restrict__ h_buf, float* __restrict__ c_state,
    float* __restrict__ xlast, int* __restrict__ flags,
    int t0, int nsteps)
{
    const int tid  = threadIdx.x;
    const int w    = tid >> 6;          // 0..3
    const int lane = tid & 63;
    const int lr   = lane & 15;
    const int p    = lane >> 4;
    const int cs   = blockIdx.x >> 6;   // 0..3
    const int rg   = blockIdx.x & 63;   // 0..63 (32-row group)
    const int r0   = rg * 32;
    const int e    = cs * 64 + w * 16 + lr;

    __shared__ __align__(16) short h_f[2][8][512];   // swizzled frag-major, 16KB
    __shared__ __align__(16) short h_o[32][64];      // own-slice staging, 4KB
    __shared__ int s_len[32];
    if (tid < 32) s_len[tid] = length[r0 + tid];

    // ---- R slice -> registers (resident across all steps) ----
    short8 bw[4][8];
    {
        const short* wb = Wcoop + ((size_t)((cs * 4 + w) * 4)) * 8 * 512 + lane * 8;
        #pragma unroll
        for (int g = 0; g < 4; ++g)
            #pragma unroll
            for (int kk = 0; kk < 8; ++kk)
                bw[g][kk] = *(const short8*)(wb + (size_t)(g * 8 + kk) * 512);
    }

    float bias[4];
    #pragma unroll
    for (int g = 0; g < 4; ++g) bias[g] = b[g * 256 + e];

    float creg[2][4];
    if (t0 == 0) {
        #pragma unroll
        for (int rf = 0; rf < 2; ++rf)
            #pragma unroll
            for (int rr = 0; rr < 4; ++rr) creg[rf][rr] = 0.f;
    } else {
        #pragma unroll
        for (int rf = 0; rf < 2; ++rf)
            #pragma unroll
            for (int rr = 0; rr < 4; ++rr)
                creg[rf][rr] = c_state[(size_t)(r0 + rf * 16 + p * 4 + rr) * E_DIM + e];
    }
    __syncthreads();

    int len_r[2][4];
    #pragma unroll
    for (int rf = 0; rf < 2; ++rf)
        #pragma unroll
        for (int rr = 0; rr < 4; ++rr)
            len_r[rf][rr] = s_len[rf * 16 + p * 4 + rr];

    const uint64_t slot_addr = (uint64_t)(uintptr_t)(flags + rg * 32 + cs);
    const uint64_t line_addr = (uint64_t)(uintptr_t)(flags + rg * 32);
    int bcnt = 0;

#define PEERS_BARRIER()                                                        \
    do {                                                                       \
        ++bcnt;                                                                \
        __syncthreads(); /* drains vmcnt: sc h-stores complete */              \
        if (tid == 0) {                                                        \
            asm volatile("global_store_dword %0, %1, off sc0 sc1"              \
                         :: "v"(slot_addr), "v"(bcnt) : "memory");             \
            i32x4 fv;                                                          \
            do {                                                               \
                asm volatile("global_load_dwordx4 %0, %1, off sc0 sc1\n\t"     \
                             "s_waitcnt vmcnt(0)"                              \
                             : "=v"(fv) : "v"(line_addr) : "memory");          \
            } while (fv[0] < bcnt || fv[1] < bcnt ||                           \
                     fv[2] < bcnt || fv[3] < bcnt);                            \
        }                                                                      \
        __syncthreads();                                                       \
    } while (0)

    // ---- chunk-0 init: zero own slice of h_buf parity 0 ----
    if (t0 == 0) {
        const i32x4 z4 = {0, 0, 0, 0};
        const int row = tid >> 3, seg = tid & 7;   // 32 rows x 8 segs
        const uint64_t dst = (uint64_t)(uintptr_t)(h_buf +
            (size_t)(r0 + row) * E_DIM + cs * 64 + seg * 8);
        asm volatile("global_store_dwordx4 %0, %1, off sc0 sc1"
                     :: "v"(dst), "v"(z4) : "memory");
        PEERS_BARRIER();
    }

    // hoisted invariants
    const short* hb0 = h_buf;
    const short* hb1 = h_buf + (size_t)N_BATCH * E_DIM;
    const size_t coloff = (size_t)((cs * 2 + (w >> 1)) * 8 + (w & 1) * 4) * 256 +
                          lane * 4;   // + g*256 per gate
    const size_t rowoff0 = (size_t)(2 * rg + 0) * TCHUNK * 16384;
    const size_t rowoff1 = (size_t)(2 * rg + 1) * TCHUNK * 16384;

#define XZ_BASE(T, RFOFF)                                                      \
    ((((((T) / TCHUNK) & 1) ? xz1 : xz0)) + (RFOFF) +                          \
     (size_t)((T) % TCHUNK) * 16384 + coloff)

    // ---- prefetch xz for first step ----
    short4v xv[2][4];
    {
        const short* b0p = XZ_BASE(t0, rowoff0);
        const short* b1p = XZ_BASE(t0, rowoff1);
        #pragma unroll
        for (int g = 0; g < 4; ++g) {
            xv[0][g] = *(const short4v*)(b0p + g * 256);
            xv[1][g] = *(const short4v*)(b1p + g * 256);
        }
    }

    // this thread's coop-load geometry (4 chunks, coalesced)
    const int ld_row = tid >> 5;           // base rows: tid>>5 + it*8
    const int ld_ch  = tid & 31;
    const int ld_kk  = ld_ch >> 2;

    for (int s = 0; s < nsteps; ++s) {
        const int t = t0 + s;
        const short* hb_r = (t & 1) ? hb1 : hb0;

        // ---- stage h(t): coalesced sc0sc1 load -> swizzled LDS ----
        {
            short8 ld[4];
            #pragma unroll
            for (int it = 0; it < 4; ++it) {
                const int row = ld_row + it * 8;
                const uint64_t src = (uint64_t)(uintptr_t)(hb_r +
                    (size_t)(r0 + row) * E_DIM + ld_ch * 8);
                asm volatile("global_load_dwordx4 %0, %1, off sc0 sc1"
                             : "=&v"(ld[it]) : "v"(src) : "memory");
            }
            asm volatile("s_waitcnt vmcnt(0)" ::: "memory");
            #pragma unroll
            for (int it = 0; it < 4; ++it) {
                const int row  = ld_row + it * 8;
                const int slot = (((ld_ch & 3) * 16) + (row & 15)) ^ ld_kk;
                *(short8*)&h_f[row >> 4][ld_kk][slot * 8] = ld[it];
            }
        }
        __syncthreads();

        // acc init from prefetched xz (registers)
        f32x4 acc[2][4];
        #pragma unroll
        for (int rf = 0; rf < 2; ++rf)
            #pragma unroll
            for (int g = 0; g < 4; ++g)
                #pragma unroll
                for (int rr = 0; rr < 4; ++rr)
                    acc[rf][g][rr] = bf2f((unsigned short)xv[rf][g][rr]);

        // ---- h @ R : a-frags from swizzled LDS, weights from registers ----
        #pragma unroll
        for (int kk = 0; kk < 8; ++kk) {
            const int sl = (lane ^ kk) * 8;
            short8 a0 = *(const short8*)&h_f[0][kk][sl];
            short8 a1 = *(const short8*)&h_f[1][kk][sl];
            #pragma unroll
            for (int g = 0; g < 4; ++g) {
                acc[0][g] = __builtin_amdgcn_mfma_f32_16x16x32_bf16(
                    a0, bw[g][kk], acc[0][g], 0, 0, 0);
                acc[1][g] = __builtin_amdgcn_mfma_f32_16x16x32_bf16(
                    a1, bw[g][kk], acc[1][g], 0, 0, 0);
            }
        }

        // next-step xz prefetch (may cross chunk parity)
        if (s + 1 < nsteps) {
            const short* b0p = XZ_BASE(t + 1, rowoff0);
            const short* b1p = XZ_BASE(t + 1, rowoff1);
            #pragma unroll
            for (int g = 0; g < 4; ++g) {
                xv[0][g] = *(const short4v*)(b0p + g * 256);
                xv[1][g] = *(const short4v*)(b1p + g * 256);
            }
        }

        // ---- gates in registers; stage h slice into LDS ----
        #pragma unroll
        for (int rf = 0; rf < 2; ++rf) {
            #pragma unroll
            for (int rr = 0; rr < 4; ++rr) {
                float zi = acc[rf][0][rr] + bias[0];
                float zf = acc[rf][1][rr] + bias[1];
                float zg = acc[rf][2][rr] + bias[2];
                float zo = acc[rf][3][rr] + bias[3];
                float ig = sigf(zi), fg = sigf(zf);
                float gg = tanhfast(zg), og = sigf(zo);
                float cc = fg * creg[rf][rr] + ig * gg;
                float hh = og * tanhfast(cc);
                creg[rf][rr] = cc;
                h_o[rf * 16 + p * 4 + rr][w * 16 + lr] = f2bf(hh);
                const int row = r0 + rf * 16 + p * 4 + rr;
                if (t == len_r[rf][rr] - 1)
                    xlast[(size_t)row * E_DIM + e] = hh;
            }
        }
        __syncthreads();   // h_o complete (also guards h_f reuse next step)

        // ---- coalesced sc0sc1 store of own h(t+1) slice ----
        {
            short* hb_w = (short*)(((t + 1) & 1) ? hb1 : hb0);
            const int row = tid >> 3, seg = tid & 7;
            i32x4 v = *(const i32x4*)&h_o[row][seg * 8];
            const uint64_t dst = (uint64_t)(uintptr_t)(hb_w +
                (size_t)(r0 + row) * E_DIM + cs * 64 + seg * 8);
            asm volatile("global_store_dwordx4 %0, %1, off sc0 sc1"
                         :: "v"(dst), "v"(v) : "memory");
        }

        if (s + 1 < nsteps) PEERS_BARRIER();
    }

    // ---- save c state for next dispatch ----
    #pragma unroll
    for (int rf = 0; rf < 2; ++rf)
        #pragma unroll
        for (int rr = 0; rr < 4; ++rr)
            c_state[(size_t)(r0 + rf * 16 + p * 4 + rr) * E_DIM + e] = creg[rf][rr];
#undef PEERS_BARRIER
#undef XZ_BASE
}

// ---------------------------------------------------------------------------
// Head MLP + L2 normalize (unchanged).
// ---------------------------------------------------------------------------
__global__ __launch_bounds__(256) void k_head(
    const float* __restrict__ xlast,
    const float* __restrict__ W0, const float* __restrict__ b0,
    const float* __restrict__ W1, const float* __restrict__ b1,
    float* __restrict__ out)
{
    const int n = blockIdx.x;
    const int j = threadIdx.x;

    __shared__ __align__(16) float xsh[E_DIM];
    __shared__ __align__(16) float y0[E_DIM];
    __shared__ float part[4];

    xsh[j] = xlast[(size_t)n * E_DIM + j];
    __syncthreads();

    float acc = b0[j];
    for (int k4 = 0; k4 < E_DIM; k4 += 4) {
        float4 xv = *reinterpret_cast<const float4*>(&xsh[k4]);
        #pragma unroll
        for (int kk = 0; kk < 4; ++kk)
            acc += (&xv.x)[kk] * W0[(size_t)(k4 + kk) * E_DIM + j];
    }
    y0[j] = fmaxf(acc, 0.f);
    __syncthreads();

    acc = b1[j];
    for (int k4 = 0; k4 < E_DIM; k4 += 4) {
        float4 yv = *reinterpret_cast<const float4*>(&y0[k4]);
        #pragma unroll
        for (int kk = 0; kk < 4; ++kk)
            acc += (&yv.x)[kk] * W1[(size_t)(k4 + kk) * E_DIM + j];
    }

    float sq = acc * acc;
    #pragma unroll
    for (int off = 32; off > 0; off >>= 1)
        sq += __shfl_xor(sq, off, 64);
    if ((j & 63) == 0) part[j >> 6] = sq;
    __syncthreads();
    float total = part[0] + part[1] + part[2] + part[3];

    out[(size_t)n * E_DIM + j] = acc * rsqrtf(total);
}

// ---------------------------------------------------------------------------
extern "C" void kernel_launch(void* const* d_in, const int* in_sizes, int n_in,
                              void* d_out, int out_size, void* d_ws, size_t ws_size,
                              hipStream_t stream) {
    const int*   code   = (const int*)  d_in[0];
    const float* aux    = (const float*)d_in[1];
    const int*   length = (const int*)  d_in[2];
    // d_in[3] = is_training (ignored)
    const float* W_lin  = (const float*)d_in[4];
    const float* b_lin  = (const float*)d_in[5];
    const float* K      = (const float*)d_in[6];
    const float* R      = (const float*)d_in[7];
    const float* b      = (const float*)d_in[8];
    const float* W0     = (const float*)d_in[9];
    const float* b0     = (const float*)d_in[10];
    const float* W1     = (const float*)d_in[11];
    const float* b1     = (const float*)d_in[12];
    float* out = (float*)d_out;

    // workspace layout (bytes, 16B aligned); total ~91.3 MB
    char* ws = (char*)d_ws;
    short* Wcoop   = (short*)(ws + 0);            //    524,288
    short* WfK     = (short*)(ws + 524288);       //    524,288
    short* WfL     = (short*)(ws + 1048576);      //    278,528
    float* xlast   = (float*)(ws + 1327104);      //  2,097,152
    float* c_state = (float*)(ws + 3424256);      //  2,097,152
    short* h_buf   = (short*)(ws + 5521408);      //  2,097,152 (2 parity bufs)
    int*   flags   = (int*)  (ws + 7618560);      //     24,576 (3 regions)
    short* xzp0    = (short*)(ws + 7643136);      // 41,943,040
    short* xzp1    = (short*)(ws + 49586176);     // 41,943,040

    k_zero      <<<24,  256, 0, stream>>>(flags);
    k_prep_wcoop<<<128, 256, 0, stream>>>(R, Wcoop);
    k_prep_wfk  <<<128, 256, 0, stream>>>(K, WfK);
    k_prep_wfl  <<<68,  256, 0, stream>>>(W_lin, WfL);

    // fused(c) writes xzp[c&1]; rcoop merges chunk pairs.
    k_fused<<<NFUSED, 512, 0, stream>>>(code, aux, WfL, b_lin, WfK, xzp0, 0);
    k_fused<<<NFUSED, 512, 0, stream>>>(code, aux, WfL, b_lin, WfK, xzp1, 10);
    k_rcoop<<<256, 256, 0, stream>>>(xzp0, xzp1, length, Wcoop, b, h_buf,
                                     c_state, xlast, flags + 0 * 2048, 0, 20);
    k_fused<<<NFUSED, 512, 0, stream>>>(code, aux, WfL, b_lin, WfK, xzp0, 20);
    k_fused<<<NFUSED, 512, 0, stream>>>(code, aux, WfL, b_lin, WfK, xzp1, 30);
    k_rcoop<<<256, 256, 0, stream>>>(xzp0, xzp1, length, Wcoop, b, h_buf,
                                     c_state, xlast, flags + 1 * 2048, 20, 20);
    k_fused<<<NFUSED, 512, 0, stream>>>(code, aux, WfL, b_lin, WfK, xzp0, 40);
    k_rcoop<<<256, 256, 0, stream>>>(xzp0, xzp1, length, Wcoop, b, h_buf,
                                     c_state, xlast, flags + 2 * 2048, 40, 10);

    k_head<<<N_BATCH, 256, 0, stream>>>(xlast, W0, b0, W1, b1, out);
}